// Round 10
// baseline (168.747 us; speedup 1.0000x reference)
//
#include <hip/hip_runtime.h>
#include <hip/hip_bf16.h>

#define DD 256
#define NROWS 16384

typedef float f32x4 __attribute__((ext_vector_type(4)));
typedef __bf16 bf16x8 __attribute__((ext_vector_type(8)));

// ---------------------------------------------------------------------------
// K1: Wc = Wout @ Wv (bf16), bc = bout + Wout @ bv.   [R5 version, unchanged]
// Grid 1024 = 256 rows x 4 col-groups -> 4 blocks/CU, 16 waves/CU.
// ---------------------------------------------------------------------------
__global__ __launch_bounds__(256) void wc_bc_kernel(
    const float* __restrict__ Wqkv, const float* __restrict__ bqkv,
    const float* __restrict__ Wout, const float* __restrict__ bout,
    __bf16* __restrict__ Wc, float* __restrict__ bc) {
  __shared__ float part[4][64];
  __shared__ float red[4];
  const int b = blockIdx.x;
  const int i = b >> 2;  // Wc row
  const int qc = b & 3;  // column group
  const int t = threadIdx.x;
  const int w = t >> 6;  // d-slice
  const int q = t & 63;  // column within group
  const int c0 = qc * 64;
  const float* __restrict__ Wv = Wqkv + 2 * DD * DD;
  const float* __restrict__ bv = bqkv + 2 * DD;
  const float* __restrict__ wrow = Wout + (size_t)i * DD;

  float acc = 0.f;
  const float* wvp = Wv + (size_t)(w * 64) * DD + c0 + q;
#pragma unroll 8
  for (int dd = 0; dd < 64; ++dd)
    acc += wrow[w * 64 + dd] * wvp[(size_t)dd * DD];  // wrow: s_load (uniform)
  part[w][q] = acc;

  if (qc == 0) {  // bc[i]
    const int d = w * 64 + q;
    float p = wrow[d] * bv[d];
#pragma unroll
    for (int off = 32; off > 0; off >>= 1) p += __shfl_down(p, off);
    if (q == 0) red[w] = p;
  }
  __syncthreads();
  if (w == 0) {
    float s = part[0][q] + part[1][q] + part[2][q] + part[3][q];
    Wc[(size_t)i * DD + c0 + q] = (__bf16)s;
    if (qc == 0 && q == 0) bc[i] = bout[i] + red[0] + red[1] + red[2] + red[3];
  }
}

// ---------------------------------------------------------------------------
// K2: out = x + x @ Wc^T + bc.   [R5 version, unchanged -- IDEMPOTENT]
// Launched 8x this round to extract its true warm per-dispatch cost from
// dur_us arithmetic (top-5 rocprof slots are saturated by harness fills).
// ---------------------------------------------------------------------------
#define RPB 16
__global__ __launch_bounds__(256, 4) void knn_attn_main(
    const float* __restrict__ x, const __bf16* __restrict__ Wc,
    const float* __restrict__ bc, float* __restrict__ out) {
  __shared__ float xs[RPB * DD];  // 16 KiB, XOR-swizzled (16B granule)

  const int t = threadIdx.x;
  const int w = t >> 6;
  const int l = t & 63;
  const int R0 = blockIdx.x * RPB;
  const int c0 = w * 64;
  const int lr = l & 15;  // fragment row
  const int g = l >> 4;   // k-group
  const int lk = g * 8;   // k offset

  {
    const int r = t >> 4, c = t & 15;
    const float* src = x + (size_t)(R0 + r) * DD + c * 16;
    f32x4 v0 = *(const f32x4*)(src + 0);
    f32x4 v1 = *(const f32x4*)(src + 4);
    f32x4 v2 = *(const f32x4*)(src + 8);
    f32x4 v3 = *(const f32x4*)(src + 12);
    const int base = r * 1024 + c * 64;
    const int sw = (r & 7) << 4;
    *(f32x4*)((char*)xs + ((base + 0) ^ sw)) = v0;
    *(f32x4*)((char*)xs + ((base + 16) ^ sw)) = v1;
    *(f32x4*)((char*)xs + ((base + 32) ^ sw)) = v2;
    *(f32x4*)((char*)xs + ((base + 48) ^ sw)) = v3;
  }
  __syncthreads();

  const int rsw = (lr & 7) << 4;
  bf16x8 xf[8];
#pragma unroll
  for (int ks = 0; ks < 8; ++ks) {
    const int b0 = lr * 1024 + (lk + ks * 32) * 4;
    f32x4 lo = *(const f32x4*)((const char*)xs + ((b0 + 0) ^ rsw));
    f32x4 hi = *(const f32x4*)((const char*)xs + ((b0 + 16) ^ rsw));
    bf16x8 v;
#pragma unroll
    for (int j = 0; j < 4; ++j) {
      v[j] = (__bf16)lo[j];
      v[4 + j] = (__bf16)hi[j];
    }
    xf[ks] = v;
  }

  f32x4 acc[4] = {};
#pragma unroll
  for (int ct = 0; ct < 4; ++ct) {
    const __bf16* wr = Wc + (size_t)(c0 + ct * 16 + lr) * DD + lk;
    bf16x8 b0 = *(const bf16x8*)(wr + 0 * 32);
    bf16x8 b1 = *(const bf16x8*)(wr + 1 * 32);
    bf16x8 b2 = *(const bf16x8*)(wr + 2 * 32);
    bf16x8 b3 = *(const bf16x8*)(wr + 3 * 32);
    bf16x8 b4 = *(const bf16x8*)(wr + 4 * 32);
    bf16x8 b5 = *(const bf16x8*)(wr + 5 * 32);
    bf16x8 b6 = *(const bf16x8*)(wr + 6 * 32);
    bf16x8 b7 = *(const bf16x8*)(wr + 7 * 32);
    acc[ct] = __builtin_amdgcn_mfma_f32_16x16x32_bf16(b0, xf[0], acc[ct], 0, 0, 0);
    acc[ct] = __builtin_amdgcn_mfma_f32_16x16x32_bf16(b1, xf[1], acc[ct], 0, 0, 0);
    acc[ct] = __builtin_amdgcn_mfma_f32_16x16x32_bf16(b2, xf[2], acc[ct], 0, 0, 0);
    acc[ct] = __builtin_amdgcn_mfma_f32_16x16x32_bf16(b3, xf[3], acc[ct], 0, 0, 0);
    acc[ct] = __builtin_amdgcn_mfma_f32_16x16x32_bf16(b4, xf[4], acc[ct], 0, 0, 0);
    acc[ct] = __builtin_amdgcn_mfma_f32_16x16x32_bf16(b5, xf[5], acc[ct], 0, 0, 0);
    acc[ct] = __builtin_amdgcn_mfma_f32_16x16x32_bf16(b6, xf[6], acc[ct], 0, 0, 0);
    acc[ct] = __builtin_amdgcn_mfma_f32_16x16x32_bf16(b7, xf[7], acc[ct], 0, 0, 0);
  }

#pragma unroll
  for (int ct = 0; ct < 4; ++ct) {
    const int col = c0 + ct * 16 + g * 4;
    f32x4 xin = *(const f32x4*)((const char*)xs + ((lr * 1024 + col * 4) ^ rsw));
    f32x4 bias = *(const f32x4*)(bc + col);
    *(f32x4*)(out + (size_t)(R0 + lr) * DD + col) = acc[ct] + xin + bias;
  }
}

extern "C" void kernel_launch(void* const* d_in, const int* in_sizes, int n_in,
                              void* d_out, int out_size, void* d_ws, size_t ws_size,
                              hipStream_t stream) {
  const float* x = (const float*)d_in[0];
  const float* Wqkv = (const float*)d_in[1];
  const float* bqkv = (const float*)d_in[2];
  const float* Wout = (const float*)d_in[3];
  const float* bout = (const float*)d_in[4];
  float* out = (float*)d_out;

  __bf16* Wc = (__bf16*)d_ws;                                   // 128 KiB
  float* bc = (float*)((char*)d_ws + DD * DD * sizeof(__bf16)); // +1 KiB

  wc_bc_kernel<<<4 * DD, 256, 0, stream>>>(Wqkv, bqkv, Wout, bout, Wc, bc);
  // K2 is idempotent: launch 8x to expose its warm per-dispatch cost via
  // dur_us arithmetic (dur ~= floor + 7*K2_warm, or stays at floor).
  for (int rep = 0; rep < 8; ++rep)
    knn_attn_main<<<NROWS / RPB, 256, 0, stream>>>(x, Wc, bc, out);
}

// Round 11
// 24.351 us; speedup vs baseline: 6.9298x; 6.9298x over previous
//
#include <hip/hip_runtime.h>
#include <hip/hip_bf16.h>

#define DD 256
#define NROWS 16384
#define TILES 8
#define TROWS 16

typedef float f32x4 __attribute__((ext_vector_type(4)));
typedef __bf16 bf16x4 __attribute__((ext_vector_type(4)));
typedef __bf16 bf16x8 __attribute__((ext_vector_type(8)));

__device__ __forceinline__ void gl2lds16(const void* g, void* l) {
  __builtin_amdgcn_global_load_lds(
      (const __attribute__((address_space(1))) void*)g,
      (__attribute__((address_space(3))) void*)l, 16, 0, 0);
}

// ---------------------------------------------------------------------------
// K1: Wc = Wout @ Wv (bf16), bc = bout + Wout @ bv.  256 blocks = 1 row each.
// Lane l owns cols 4l..4l+3 (f32x4, full 1KB/inst coalescing); wave w owns
// d-slice [64w,+64) with Wout coeffs preloaded to regs; all 64 Wv loads are
// independent and fully unrolled (max MLP).
// ---------------------------------------------------------------------------
__global__ __launch_bounds__(256) void wc_bc_kernel(
    const float* __restrict__ Wqkv, const float* __restrict__ bqkv,
    const float* __restrict__ Wout, const float* __restrict__ bout,
    __bf16* __restrict__ Wc, float* __restrict__ bc) {
  __shared__ f32x4 part[4][64];
  __shared__ float red[4];
  const int i = blockIdx.x;
  const int t = threadIdx.x;
  const int w = t >> 6, l = t & 63;
  const float* __restrict__ Wv = Wqkv + 2 * DD * DD;
  const float* __restrict__ bv = bqkv + 2 * DD;
  const float* __restrict__ wrow = Wout + (size_t)i * DD;

  f32x4 wr[16];  // wave's 64 Wout coefficients (uniform broadcast loads)
#pragma unroll
  for (int k = 0; k < 16; ++k) wr[k] = *(const f32x4*)(wrow + w * 64 + k * 4);

  const float* wvp = Wv + (size_t)(w * 64) * DD + l * 4;
  f32x4 a0 = {0.f, 0.f, 0.f, 0.f}, a1 = {0.f, 0.f, 0.f, 0.f};
  f32x4 a2 = {0.f, 0.f, 0.f, 0.f}, a3 = {0.f, 0.f, 0.f, 0.f};
#pragma unroll
  for (int k = 0; k < 16; ++k) {
    a0 += wr[k][0] * *(const f32x4*)(wvp + (size_t)(4 * k + 0) * DD);
    a1 += wr[k][1] * *(const f32x4*)(wvp + (size_t)(4 * k + 1) * DD);
    a2 += wr[k][2] * *(const f32x4*)(wvp + (size_t)(4 * k + 2) * DD);
    a3 += wr[k][3] * *(const f32x4*)(wvp + (size_t)(4 * k + 3) * DD);
  }
  part[w][l] = (a0 + a1) + (a2 + a3);

  {  // bc partial
    const int d = w * 64 + l;
    float p = wrow[d] * bv[d];
#pragma unroll
    for (int off = 32; off > 0; off >>= 1) p += __shfl_down(p, off);
    if (l == 0) red[w] = p;
  }
  __syncthreads();
  if (w == 0) {
    f32x4 s = (part[0][l] + part[1][l]) + (part[2][l] + part[3][l]);
    bf16x4 o;
#pragma unroll
    for (int j = 0; j < 4; ++j) o[j] = (__bf16)s[j];
    *(bf16x4*)(Wc + (size_t)i * DD + l * 4) = o;
    if (l == 0) bc[i] = bout[i] + red[0] + red[1] + red[2] + red[3];
  }
}

// ---------------------------------------------------------------------------
// K2: out = x + x @ Wc^T + bc.  Weight-amortized + software-pipelined.
// Block = 64 out-cols x 128 rows (8 tiles of 16). Wc slice (32KB) staged ONCE
// via global_load_lds w/ pre-swizzled source (R7-verified); x tiles fp32 in
// double-buffered swizzled LDS (R5-verified frag/epilogue paths). Next tile's
// loads issue before compute; consumed by ds_write after compute, so the
// vmcnt wait lands post-MFMA. Grid 512, 64KB LDS -> 2 blocks/CU resident.
// cg = bid>>7 so the 4 blocks sharing x-rows are == mod 8 (same XCD L2).
// ---------------------------------------------------------------------------
__global__ __launch_bounds__(256, 2) void knn_attn_main(
    const float* __restrict__ x, const __bf16* __restrict__ Wc,
    const float* __restrict__ bc, float* __restrict__ out) {
  __shared__ __bf16 wc_s[64 * DD];     // 32 KiB bf16 weights, swizzled
  __shared__ float xs[2][TROWS * DD];  // 2 x 16 KiB fp32 x tiles, swizzled

  const int t = threadIdx.x;
  const int w = t >> 6, l = t & 63;
  const int cg = blockIdx.x >> 7;   // 0..3: col group
  const int rb = blockIdx.x & 127;  // 0..127: row block
  const int C0 = cg * 64;
  const int Rbase = rb * (TILES * TROWS);

  // Stage Wc rows [C0, C0+64): linear LDS dest + inverse-swizzled source.
#pragma unroll
  for (int j = 0; j < 8; ++j) {
    const int L = (w * 8 + j) * 1024 + l * 16;
    const int row = L >> 9;
    const int srow = (L & 511) ^ ((row & 7) << 4);
    gl2lds16((const char*)Wc + (size_t)(C0 + row) * 512 + srow,
             (char*)wc_s + (w * 8192 + j * 1024));
  }

  // staging geometry: thread -> (row sr, 16-float segment sc)
  const int sr = t >> 4, sc = t & 15;
  const int ssw = (sr & 7) << 4;
  const int sbase = sr * 1024 + sc * 64;

  // fragment geometry (R5/R7-verified)
  const int xrow = l & 15, g4 = l >> 4;
  const int rsw = (xrow & 7) << 4;
  const int rA = w * 16 + xrow;
  const int csw = (rA & 7) << 4;
  const int ocol = C0 + w * 16 + g4 * 4;
  const f32x4 bias = *(const f32x4*)(bc + ocol);  // hoisted; bc incl. bout

  // prologue: tile 0
  const float* s0 = x + (size_t)(Rbase + sr) * DD + sc * 16;
  f32x4 r0 = *(const f32x4*)(s0 + 0);
  f32x4 r1 = *(const f32x4*)(s0 + 4);
  f32x4 r2 = *(const f32x4*)(s0 + 8);
  f32x4 r3 = *(const f32x4*)(s0 + 12);
  {
    char* xb = (char*)&xs[0][0];
    *(f32x4*)(xb + ((sbase + 0) ^ ssw)) = r0;
    *(f32x4*)(xb + ((sbase + 16) ^ ssw)) = r1;
    *(f32x4*)(xb + ((sbase + 32) ^ ssw)) = r2;
    *(f32x4*)(xb + ((sbase + 48) ^ ssw)) = r3;
  }
  __syncthreads();  // drains Wc DMA + tile-0 writes

  for (int i = 0; i < TILES; ++i) {
    if (i + 1 < TILES) {  // issue next tile's loads (fly under compute)
      const float* sn =
          x + (size_t)(Rbase + (i + 1) * TROWS + sr) * DD + sc * 16;
      r0 = *(const f32x4*)(sn + 0);
      r1 = *(const f32x4*)(sn + 4);
      r2 = *(const f32x4*)(sn + 8);
      r3 = *(const f32x4*)(sn + 12);
    }

    // compute tile i
    const char* xb = (const char*)&xs[i & 1][0];
    f32x4 acc = {0.f, 0.f, 0.f, 0.f};
#pragma unroll
    for (int ks = 0; ks < 8; ++ks) {
      const int kb = ks * 64 + g4 * 16;        // byte offset in bf16 row
      const int xo = xrow * 1024 + (kb << 1);  // byte offset in fp32 row
      f32x4 lo = *(const f32x4*)(xb + ((xo + 0) ^ rsw));
      f32x4 hi = *(const f32x4*)(xb + ((xo + 16) ^ rsw));
      bf16x8 bfr;
#pragma unroll
      for (int j = 0; j < 4; ++j) {
        bfr[j] = (__bf16)lo[j];
        bfr[4 + j] = (__bf16)hi[j];
      }
      bf16x8 af = *(const bf16x8*)((const char*)wc_s + ((rA * 512 + kb) ^ csw));
      acc = __builtin_amdgcn_mfma_f32_16x16x32_bf16(af, bfr, acc, 0, 0, 0);
    }
    {  // epilogue: D col(l&15)=x-row, rowquad g4*4+reg = out-col (verified)
      f32x4 xres = *(const f32x4*)(xb + ((xrow * 1024 + ocol * 4) ^ rsw));
      *(f32x4*)(out + (size_t)(Rbase + i * TROWS + xrow) * DD + ocol) =
          acc + xres + bias;
    }

    if (i + 1 < TILES) {  // write next tile (vmcnt wait lands here)
      char* xbn = (char*)&xs[(i + 1) & 1][0];
      *(f32x4*)(xbn + ((sbase + 0) ^ ssw)) = r0;
      *(f32x4*)(xbn + ((sbase + 16) ^ ssw)) = r1;
      *(f32x4*)(xbn + ((sbase + 32) ^ ssw)) = r2;
      *(f32x4*)(xbn + ((sbase + 48) ^ ssw)) = r3;
    }
    __syncthreads();
  }
}

extern "C" void kernel_launch(void* const* d_in, const int* in_sizes, int n_in,
                              void* d_out, int out_size, void* d_ws, size_t ws_size,
                              hipStream_t stream) {
  const float* x = (const float*)d_in[0];
  const float* Wqkv = (const float*)d_in[1];
  const float* bqkv = (const float*)d_in[2];
  const float* Wout = (const float*)d_in[3];
  const float* bout = (const float*)d_in[4];
  float* out = (float*)d_out;

  __bf16* Wc = (__bf16*)d_ws;                                   // 128 KiB
  float* bc = (float*)((char*)d_ws + DD * DD * sizeof(__bf16)); // +1 KiB

  wc_bc_kernel<<<DD, 256, 0, stream>>>(Wqkv, bqkv, Wout, bout, Wc, bc);
  knn_attn_main<<<512, 256, 0, stream>>>(x, Wc, bc, out);
}

// Round 12
// 22.816 us; speedup vs baseline: 7.3961x; 1.0673x over previous
//
#include <hip/hip_runtime.h>
#include <hip/hip_bf16.h>

#define DD 256
#define NROWS 16384
#define TILES 4
#define TROWS 16

typedef float f32x4 __attribute__((ext_vector_type(4)));
typedef __bf16 bf16x4 __attribute__((ext_vector_type(4)));
typedef __bf16 bf16x8 __attribute__((ext_vector_type(8)));

__device__ __forceinline__ void gl2lds16(const void* g, void* l) {
  __builtin_amdgcn_global_load_lds(
      (const __attribute__((address_space(1))) void*)g,
      (__attribute__((address_space(3))) void*)l, 16, 0, 0);
}

__device__ __forceinline__ bf16x8 cvt8(f32x4 lo, f32x4 hi) {
  bf16x8 v;
#pragma unroll
  for (int j = 0; j < 4; ++j) {
    v[j] = (__bf16)lo[j];
    v[4 + j] = (__bf16)hi[j];
  }
  return v;
}

// ---------------------------------------------------------------------------
// K1: Wc = Wout @ Wv (bf16), bc = bout + Wout @ bv.  [R11 version, unchanged]
// ---------------------------------------------------------------------------
__global__ __launch_bounds__(256) void wc_bc_kernel(
    const float* __restrict__ Wqkv, const float* __restrict__ bqkv,
    const float* __restrict__ Wout, const float* __restrict__ bout,
    __bf16* __restrict__ Wc, float* __restrict__ bc) {
  __shared__ f32x4 part[4][64];
  __shared__ float red[4];
  const int i = blockIdx.x;
  const int t = threadIdx.x;
  const int w = t >> 6, l = t & 63;
  const float* __restrict__ Wv = Wqkv + 2 * DD * DD;
  const float* __restrict__ bv = bqkv + 2 * DD;
  const float* __restrict__ wrow = Wout + (size_t)i * DD;

  f32x4 wr[16];
#pragma unroll
  for (int k = 0; k < 16; ++k) wr[k] = *(const f32x4*)(wrow + w * 64 + k * 4);

  const float* wvp = Wv + (size_t)(w * 64) * DD + l * 4;
  f32x4 a0 = {0.f, 0.f, 0.f, 0.f}, a1 = {0.f, 0.f, 0.f, 0.f};
  f32x4 a2 = {0.f, 0.f, 0.f, 0.f}, a3 = {0.f, 0.f, 0.f, 0.f};
#pragma unroll
  for (int k = 0; k < 16; ++k) {
    a0 += wr[k][0] * *(const f32x4*)(wvp + (size_t)(4 * k + 0) * DD);
    a1 += wr[k][1] * *(const f32x4*)(wvp + (size_t)(4 * k + 1) * DD);
    a2 += wr[k][2] * *(const f32x4*)(wvp + (size_t)(4 * k + 2) * DD);
    a3 += wr[k][3] * *(const f32x4*)(wvp + (size_t)(4 * k + 3) * DD);
  }
  part[w][l] = (a0 + a1) + (a2 + a3);

  {
    const int d = w * 64 + l;
    float p = wrow[d] * bv[d];
#pragma unroll
    for (int off = 32; off > 0; off >>= 1) p += __shfl_down(p, off);
    if (l == 0) red[w] = p;
  }
  __syncthreads();
  if (w == 0) {
    f32x4 s = (part[0][l] + part[1][l]) + (part[2][l] + part[3][l]);
    bf16x4 o;
#pragma unroll
    for (int j = 0; j < 4; ++j) o[j] = (__bf16)s[j];
    *(bf16x4*)(Wc + (size_t)i * DD + l * 4) = o;
    if (l == 0) bc[i] = bout[i] + red[0] + red[1] + red[2] + red[3];
  }
}

// ---------------------------------------------------------------------------
// K2: out = x + x @ Wc^T + bc.
// vs R11: x staged as BF16 (cvt once at staging; 8 ds_read + 8 MFMA per
// tile, no inner-loop cvt), 48KB LDS + launch_bounds(256,3) -> 3 blocks/CU,
// grid 1024 (4 cg x 256 rb, TILES=4), one barrier per tile (double buffer).
// Residual = exact fp32 x re-read from global (L2-hot; R5-verified).
// The 4 blocks sharing x rows are bid = rb + 256k -> same XCD (256%8==0).
// ---------------------------------------------------------------------------
__global__ __launch_bounds__(256, 3) void knn_attn_main(
    const float* __restrict__ x, const __bf16* __restrict__ Wc,
    const float* __restrict__ bc, float* __restrict__ out) {
  __shared__ __bf16 wc_s[64 * DD];        // 32 KiB weights, swizzled
  __shared__ __bf16 xs[2][TROWS * DD];    // 2 x 8 KiB bf16 x tiles, swizzled

  const int t = threadIdx.x;
  const int w = t >> 6, l = t & 63;
  const int cg = blockIdx.x >> 8;   // 0..3: col group
  const int rb = blockIdx.x & 255;  // 0..255: row block
  const int C0 = cg * 64;
  const int Rbase = rb * (TILES * TROWS);  // 64 rows per block

  // Stage Wc rows [C0, C0+64): linear LDS dest + inverse-swizzled source.
#pragma unroll
  for (int j = 0; j < 8; ++j) {
    const int L = (w * 8 + j) * 1024 + l * 16;
    const int row = L >> 9;
    const int srow = (L & 511) ^ ((row & 7) << 4);
    gl2lds16((const char*)Wc + (size_t)(C0 + row) * 512 + srow,
             (char*)wc_s + (w * 8192 + j * 1024));
  }

  // staging geometry: thread -> (row sr, 16-float segment sc)
  const int sr = t >> 4, sc = t & 15;
  const int ssw = (sr & 7) << 4;
  const int sbase = sr * 512 + sc * 32;  // bf16 row = 512 B

  // fragment geometry (R5/R7/R11-verified)
  const int xrow = l & 15, g4 = l >> 4;
  const int rsw = (xrow & 7) << 4;
  const int rA = w * 16 + xrow;
  const int csw = (rA & 7) << 4;
  const int ocol = C0 + w * 16 + g4 * 4;
  const f32x4 bias = *(const f32x4*)(bc + ocol);  // bc includes bout

  // prologue: tile 0
  {
    const float* s0 = x + (size_t)(Rbase + sr) * DD + sc * 16;
    f32x4 a = *(const f32x4*)(s0 + 0);
    f32x4 b = *(const f32x4*)(s0 + 4);
    f32x4 c = *(const f32x4*)(s0 + 8);
    f32x4 d = *(const f32x4*)(s0 + 12);
    char* xb = (char*)&xs[0][0];
    *(bf16x8*)(xb + ((sbase + 0) ^ ssw)) = cvt8(a, b);
    *(bf16x8*)(xb + ((sbase + 16) ^ ssw)) = cvt8(c, d);
  }
  __syncthreads();  // drains Wc DMA + tile-0 ds_writes

  for (int i = 0; i < TILES; ++i) {
    f32x4 a, b, c, d;
    if (i + 1 < TILES) {  // issue next tile's loads under compute
      const float* sn = x + (size_t)(Rbase + (i + 1) * TROWS + sr) * DD + sc * 16;
      a = *(const f32x4*)(sn + 0);
      b = *(const f32x4*)(sn + 4);
      c = *(const f32x4*)(sn + 8);
      d = *(const f32x4*)(sn + 12);
    }

    // compute tile i: 8 ds_read_b128 (x) + 8 ds_read_b128 (w) + 8 MFMA
    const char* xb = (const char*)&xs[i & 1][0];
    f32x4 acc = {0.f, 0.f, 0.f, 0.f};
#pragma unroll
    for (int ks = 0; ks < 8; ++ks) {
      const int kb = ks * 64 + g4 * 16;
      bf16x8 bfr = *(const bf16x8*)(xb + ((xrow * 512 + kb) ^ rsw));
      bf16x8 af = *(const bf16x8*)((const char*)wc_s + ((rA * 512 + kb) ^ csw));
      acc = __builtin_amdgcn_mfma_f32_16x16x32_bf16(af, bfr, acc, 0, 0, 0);
    }
    {  // epilogue: D col(l&15)=x-row, rowquad g4*4+reg = out-col (verified)
      const size_t idx = (size_t)(Rbase + i * TROWS + xrow) * DD + ocol;
      f32x4 xres = *(const f32x4*)(x + idx);  // exact fp32, L2-hot
      *(f32x4*)(out + idx) = acc + xres + bias;
    }

    if (i + 1 < TILES) {  // write next tile into the other buffer
      char* xbn = (char*)&xs[(i + 1) & 1][0];
      *(bf16x8*)(xbn + ((sbase + 0) ^ ssw)) = cvt8(a, b);
      *(bf16x8*)(xbn + ((sbase + 16) ^ ssw)) = cvt8(c, d);
    }
    __syncthreads();  // readers of xs[i&1] done; xs[(i+1)&1] published
  }
}

extern "C" void kernel_launch(void* const* d_in, const int* in_sizes, int n_in,
                              void* d_out, int out_size, void* d_ws, size_t ws_size,
                              hipStream_t stream) {
  const float* x = (const float*)d_in[0];
  const float* Wqkv = (const float*)d_in[1];
  const float* bqkv = (const float*)d_in[2];
  const float* Wout = (const float*)d_in[3];
  const float* bout = (const float*)d_in[4];
  float* out = (float*)d_out;

  __bf16* Wc = (__bf16*)d_ws;                                   // 128 KiB
  float* bc = (float*)((char*)d_ws + DD * DD * sizeof(__bf16)); // +1 KiB

  wc_bc_kernel<<<DD, 256, 0, stream>>>(Wqkv, bqkv, Wout, bout, Wc, bc);
  knn_attn_main<<<1024, 256, 0, stream>>>(x, Wc, bc, out);
}